// Round 15
// baseline (47.604 us; speedup 1.0000x reference)
//
#include <hip/hip_runtime.h>

// Problem constants
#define NN 20000
#define SS 400
#define QP 60                  // floats per row
#define NG64 313               // 64-n groups (ceil(20000/64))
#define NG64P 316              // padded to multiple of 4 (waves/block)
#define NPADT (NG64P*64)       // 20224
#define NBX (NG64P/4)          // 79 main blocks (x)
#define GS 16                  // s-slices (gridDim.y)
#define SPG (SS/GS)            // 25 s per slice
#define BLK 256                // 4 waves
#define PF4TOT (NN*QP/4)       // 300000 float4 in pauli

// ws layout (floats)
#define WS_H   0                        // [400][60] heads2, r2 folded into q0
#define WS_PT  (SS*QP)                  // 24000: PT [NG64P][15][64] float4
#define WS_COV (WS_PT + NG64P*960*4)    // one-shot cov slots [GS][NPADT]
#define WS_CNT (WS_COV + GS*NPADT)      // per-bx arrival counters (int)

// prep: 316 blocks x 256. Per 64-n group: linear-coalesced pauli read ->
// LDS (stride-61 rows, conflict-free scalar transpose) -> PT [k][lane] f4
// coalesced write. Plus echo outputs, r2-folded heads table, counters/loss=0.
__global__ __launch_bounds__(BLK) void prep_kernel(
        const float* __restrict__ heads_param,
        const float* __restrict__ ratios_param,
        const float* __restrict__ pauli,
        float* __restrict__ out, float* __restrict__ ws) {
    __shared__ float ldsR[64*61];      // 64 rows, stride 61 (odd -> no bank conflict)

    const int tid = threadIdx.x;
    const int bx  = blockIdx.x;
    const int n0  = bx * 64;

    // 1) linear read of this group's 64 rows (960 float4, fully coalesced)
    for (int i = tid; i < 960; i += BLK) {
        int r = i / 15, k = i - r*15;              // row, quad
        int gidx = n0*15 + i;                      // linear f4 index
        float4 v = make_float4(0.f,0.f,0.f,0.f);
        if (gidx < PF4TOT && (n0 + r) < NN)
            v = reinterpret_cast<const float4*>(pauli)[gidx];
        ldsR[r*61 + 4*k + 0] = v.x;
        ldsR[r*61 + 4*k + 1] = v.y;
        ldsR[r*61 + 4*k + 2] = v.z;
        ldsR[r*61 + 4*k + 3] = v.w;
    }
    __syncthreads();

    // 2) transposed PT write: PT[bx][k][l], coalesced global f4 stores
    {
        float4* pt = reinterpret_cast<float4*>(ws + WS_PT) + (size_t)bx * 960;
        for (int i = tid; i < 960; i += BLK) {
            int k = i >> 6, l = i & 63;
            float4 v;
            v.x = ldsR[l*61 + 4*k + 0];
            v.y = ldsR[l*61 + 4*k + 1];
            v.z = ldsR[l*61 + 4*k + 2];
            v.w = ldsR[l*61 + 4*k + 3];
            pt[i] = v;
        }
    }

    // 3) echo outputs + r2-folded heads table + zero counters/loss
    const int gi = bx*BLK + tid;
    if (gi < SS*QP) {
        int s = gi / QP, k = gi - s*QP;
        float h = heads_param[gi];
        float h2 = h * h;
        out[1 + SS + gi] = h2;                     // heads output (unscaled)
        float rr = ratios_param[s];
        ws[WS_H + gi] = (k < 3) ? h2 * (rr*rr) : h2;  // fold r2 into q0 dot
    }
    if (gi < SS) {
        float rr = ratios_param[gi];
        out[1 + gi] = rr * rr;                     // ratios output
    }
    if (gi < NBX) reinterpret_cast<int*>(ws + WS_CNT)[gi] = 0;
    if (gi == 0) out[0] = 0.f;
}

// 4-qubit chunk: pauli in named VGPR float4s, heads in SGPR float4s
// (each VALU op uses exactly one SGPR operand - legal encoding).
#define QCHUNK(PB0, PB1, PB2, HB0, HB1, HB2)                            \
    do {                                                                \
        float d0 = PB0.x*HB0.x + PB0.y*HB0.y + PB0.z*HB0.z;             \
        float d1 = PB0.w*HB0.w + PB1.x*HB1.x + PB1.y*HB1.y;             \
        float d2 = PB1.z*HB1.z + PB1.w*HB1.w + PB2.x*HB2.x;             \
        float d3 = PB2.y*HB2.y + PB2.z*HB2.z + PB2.w*HB2.w;             \
        pr *= (d0*d1)*(d2*d3);                                          \
    } while (0)

// main: one n per lane. Pauli row resident in 60 VGPRs (loaded once,
// coalesced). Per s: 15 wave-uniform SMEM quads (60 SGPR, one batched wait)
// then 76 pure-VALU ops - deep load pipelining, nothing else on lgkmcnt.
__global__ __launch_bounds__(BLK) void main_kernel(
        const float* __restrict__ hws,   // ws + WS_H
        const float4* __restrict__ pt,   // ws + WS_PT
        float* covp,                     // ws + WS_COV [GS][NPADT] one-shot
        int*   cnt,                      // ws + WS_CNT
        const float* __restrict__ coeff,
        float* out) {
    __shared__ float red[4];
    __shared__ int   lastFlag;

    const int tid  = threadIdx.x;
    const int wave = tid >> 6;
    const int lane = tid & 63;
    const int g    = blockIdx.y;
    const int bx   = blockIdx.x;
    const int g64  = bx*4 + wave;            // this wave's 64-n group

    // Load lane's pauli row: 15 coalesced f4 from PT[g64][k][lane]
    const float4* pb = pt + (size_t)g64 * 960 + lane;
    float4 P0  = pb[0*64],  P1  = pb[1*64],  P2  = pb[2*64];
    float4 P3  = pb[3*64],  P4  = pb[4*64],  P5  = pb[5*64];
    float4 P6  = pb[6*64],  P7  = pb[7*64],  P8  = pb[8*64];
    float4 P9  = pb[9*64],  P10 = pb[10*64], P11 = pb[11*64];
    float4 P12 = pb[12*64], P13 = pb[13*64], P14 = pb[14*64];

    // block-uniform heads base for this s-slice
    const float* hbase = hws + (size_t)g * (SPG * QP);

    float acc = 0.f;
    #pragma unroll 1
    for (int s = 0; s < SPG; ++s) {
        const float4* hf = reinterpret_cast<const float4*>(hbase + s*QP);
        float4 H0  = hf[0],  H1  = hf[1],  H2  = hf[2],  H3 = hf[3], H4 = hf[4];
        float4 H5  = hf[5],  H6  = hf[6],  H7  = hf[7],  H8 = hf[8], H9 = hf[9];
        float4 H10 = hf[10], H11 = hf[11], H12 = hf[12], H13 = hf[13], H14 = hf[14];
        float pr = 1.f;
        QCHUNK(P0,  P1,  P2,  H0,  H1,  H2);
        QCHUNK(P3,  P4,  P5,  H3,  H4,  H5);
        QCHUNK(P6,  P7,  P8,  H6,  H7,  H8);
        QCHUNK(P9,  P10, P11, H9,  H10, H11);
        QCHUNK(P12, P13, P14, H12, H13, H14);
        acc += pr;                          // r2 folded into q0's heads
    }

    // one-shot partial slot (AGENT scope = coherent point, visible cross-XCD)
    const int n = g64*64 + lane;            // == bx*256 + tid
    __hip_atomic_store(covp + (size_t)g * NPADT + n, acc,
                       __ATOMIC_RELAXED, __HIP_MEMORY_SCOPE_AGENT);
    asm volatile("s_waitcnt vmcnt(0)" ::: "memory");
    __syncthreads();                        // all 4 waves' stores drained

    if (tid == 0) {
        int old = atomicAdd(cnt + bx, 1);   // device-scope arrival
        lastFlag = (old == GS - 1);
    }
    __syncthreads();

    if (lastFlag) {                         // last arriver finalizes 256 n's
        float term = 0.f;
        if (n < NN) {
            float cs = 0.f;
            #pragma unroll
            for (int g2 = 0; g2 < GS; ++g2)
                cs += __hip_atomic_load(covp + (size_t)g2 * NPADT + n,
                                        __ATOMIC_RELAXED, __HIP_MEMORY_SCOPE_AGENT);
            float c = coeff[n];
            term = (c * c) / cs;
        }
        #pragma unroll
        for (int off = 32; off; off >>= 1) term += __shfl_down(term, off);
        if (lane == 0) red[wave] = term;
        __syncthreads();
        if (tid == 0) atomicAdd(out, (red[0] + red[1]) + (red[2] + red[3]));
    }
}

extern "C" void kernel_launch(void* const* d_in, const int* in_sizes, int n_in,
                              void* d_out, int out_size, void* d_ws, size_t ws_size,
                              hipStream_t stream) {
    const float* heads_param  = (const float*)d_in[0];   // [S,Q,P]
    const float* ratios_param = (const float*)d_in[1];   // [S]
    const float* pauli        = (const float*)d_in[2];   // [N,Q,P]
    const float* coeff        = (const float*)d_in[3];   // [N]
    float* out = (float*)d_out;
    float* ws  = (float*)d_ws;

    prep_kernel<<<NG64P, BLK, 0, stream>>>(heads_param, ratios_param, pauli, out, ws);
    main_kernel<<<dim3(NBX, GS), BLK, 0, stream>>>(
        ws + WS_H, (const float4*)(ws + WS_PT), ws + WS_COV,
        (int*)(ws + WS_CNT), coeff, out);
}